// Round 9
// baseline (470.290 us; speedup 1.0000x reference)
//
#include <hip/hip_runtime.h>

#define N_NODES 10000
#define N_EDGES 100000
#define IN_CH 64
#define EDGE_DIM 16
#define HID 128
#define HEADS 4
#define HC 512          // HEADS*HID
#define LAYERS 4
#define NUM_GRAPHS 256
#define NCAT 1152       // 512(xl) + 512(xr) + 128(res) packed cols
#define LDP 136         // padded LDS stride (bf16 elems)

typedef __bf16 bf16;
typedef __bf16 bf16x8 __attribute__((ext_vector_type(8)));
typedef __bf16 bf16x4 __attribute__((ext_vector_type(4)));
typedef float floatx4 __attribute__((ext_vector_type(4)));

__device__ __forceinline__ float elu_f(float x) { return x > 0.f ? x : (__expf(x) - 1.f); }

// ---------------- weight prep: WT[l][n][k] bf16, coalesced via LDS transpose ----
__global__ __launch_bounds__(128) void k_prep_w(
    const float* __restrict__ Wl, const float* __restrict__ bl,
    const float* __restrict__ Wr, const float* __restrict__ br,
    const float* __restrict__ Wres, const float* __restrict__ bres,
    bf16* __restrict__ WT, float* __restrict__ bcat) {
    __shared__ float tile[16][129];
    int nt = blockIdx.x, i = blockIdx.y, z = blockIdx.z;
    int t = threadIdx.x;
    int n0 = nt * 128;
    const float* base = nullptr; const float* bsrc = nullptr; int ld = 0;
    if (nt < 4)       { base = Wl + (size_t)i * HID * HC + n0;            bsrc = bl + i * HC + n0;              ld = HC; }
    else if (nt < 8)  { base = Wr + (size_t)i * HID * HC + (n0 - 512);    bsrc = br + i * HC + (n0 - 512);      ld = HC; }
    else if (i > 0)   { base = Wres + (size_t)(i - 1) * HID * HID;        bsrc = bres + (size_t)(i - 1) * HID;  ld = HID; }
    if (base) {
#pragma unroll
        for (int r = 0; r < 16; r++) tile[r][t] = base[(size_t)(z * 16 + r) * ld + t];
    } else {
#pragma unroll
        for (int r = 0; r < 16; r++) tile[r][t] = 0.f;
    }
    __syncthreads();
    int n = n0 + t;
    if (z == 0) bcat[(size_t)i * NCAT + n] = base ? bsrc[t] : 0.f;
    bf16* dst = WT + ((size_t)i * NCAT + n) * HID + z * 16;
#pragma unroll
    for (int kc = 0; kc < 2; kc++) {
        bf16x8 v;
#pragma unroll
        for (int u = 0; u < 8; u++) v[u] = (bf16)tile[kc * 8 + u][t];
        *(bf16x8*)(dst + kc * 8) = v;
    }
}

// ---------------- h0 = elu(x @ Win + b_in) ----------------
__global__ __launch_bounds__(128) void k_init_h(const float* __restrict__ x,
                                                const float* __restrict__ Win,
                                                const float* __restrict__ b_in,
                                                bf16* __restrict__ h_bf) {
    __shared__ float xs[IN_CH];
    int n = blockIdx.x, t = threadIdx.x;
    if (t < IN_CH) xs[t] = x[(size_t)n * IN_CH + t];
    __syncthreads();
    float s = b_in[t];
#pragma unroll 8
    for (int k = 0; k < IN_CH; k++) s = fmaf(xs[k], Win[k * HID + t], s);
    h_bf[(size_t)n * HID + t] = (bf16)elu_f(s);
}

// ---------------- MFMA bf16 GEMM: C[M,NCAT] = A[M,128] @ WT^T + bias ------
__global__ __launch_bounds__(256, 2) void k_gemm_mfma(
    const bf16* __restrict__ A, const bf16* __restrict__ WT,
    const float* __restrict__ bcat, bf16* __restrict__ C, int M) {
    __shared__ __align__(16) unsigned short As[128 * LDP];
    __shared__ __align__(16) unsigned short Bs[128 * LDP];
    int t = threadIdx.x;
    int r0 = blockIdx.x * 128, c0 = blockIdx.y * 128;
#pragma unroll
    for (int i = 0; i < 8; i++) {
        int idx = t + i * 256;
        int row = idx >> 4;
        int ch = idx & 15;
        int r = r0 + row; if (r >= M) r = M - 1;
        uint4 va = *(const uint4*)(A + (size_t)r * HID + ch * 8);
        *(uint4*)&As[row * LDP + ch * 8] = va;
        uint4 vb = *(const uint4*)(WT + (size_t)(c0 + row) * HID + ch * 8);
        *(uint4*)&Bs[row * LDP + ch * 8] = vb;
    }
    __syncthreads();

    int wave = t >> 6, lane = t & 63;
    int wm = wave & 1, wn = wave >> 1;
    int quad = lane >> 4, lm = lane & 15;
    floatx4 zero = {0.f, 0.f, 0.f, 0.f};
    floatx4 acc[4][4];
#pragma unroll
    for (int mi = 0; mi < 4; mi++)
#pragma unroll
        for (int ni = 0; ni < 4; ni++) acc[mi][ni] = zero;

    const unsigned short* Ab = &As[(wm * 64 + lm) * LDP + quad * 8];
    const unsigned short* Bb = &Bs[(wn * 64 + lm) * LDP + quad * 8];
#pragma unroll
    for (int ks = 0; ks < 4; ks++) {
        bf16x8 af[4], bfr[4];
#pragma unroll
        for (int mi = 0; mi < 4; mi++) af[mi] = *(const bf16x8*)(Ab + mi * 16 * LDP + ks * 32);
#pragma unroll
        for (int ni = 0; ni < 4; ni++) bfr[ni] = *(const bf16x8*)(Bb + ni * 16 * LDP + ks * 32);
#pragma unroll
        for (int mi = 0; mi < 4; mi++)
#pragma unroll
            for (int ni = 0; ni < 4; ni++)
                acc[mi][ni] = __builtin_amdgcn_mfma_f32_16x16x32_bf16(bfr[ni], af[mi], acc[mi][ni], 0, 0, 0);
    }

#pragma unroll
    for (int mi = 0; mi < 4; mi++) {
        int row = r0 + wm * 64 + mi * 16 + lm;
        if (row < M) {
            bf16* crow = C + (size_t)row * NCAT;
#pragma unroll
            for (int ni = 0; ni < 4; ni++) {
                int cb = c0 + wn * 64 + ni * 16 + quad * 4;
                float4 b4 = *(const float4*)(bcat + cb);
                floatx4 v = acc[mi][ni];
                bf16x4 o = {(bf16)(v[0] + b4.x), (bf16)(v[1] + b4.y),
                            (bf16)(v[2] + b4.z), (bf16)(v[3] + b4.w)};
                *(bf16x4*)(crow + cb) = o;
            }
        }
    }
}

// ---------------- CSR build (+ per-graph node counts folded in) ----------------
__global__ void k_degree(const int* __restrict__ ei, const int* __restrict__ batch,
                         int* __restrict__ deg, int* __restrict__ cnt) {
    int e = blockIdx.x * blockDim.x + threadIdx.x;
    if (e < N_EDGES) atomicAdd(&deg[ei[N_EDGES + e]], 1);
    if (e < N_NODES) atomicAdd(&cnt[batch[e]], 1);
}

// shfl-based scan, 4 elems/thread (3 chunks of 4096 instead of 10 of 1024)
__global__ __launch_bounds__(1024) void k_scan(const int* __restrict__ deg,
                                               int* __restrict__ row_start,
                                               int* __restrict__ cursor) {
    __shared__ int wsum[16];
    __shared__ int carry_s;
    int t = threadIdx.x;
    int wave = t >> 6, lane = t & 63;
    if (t == 0) { carry_s = 0; row_start[0] = 0; }
    __syncthreads();
    for (int base = 0; base < N_NODES; base += 4096) {
        int i0 = base + t * 4;
        int v[4];
#pragma unroll
        for (int u = 0; u < 4; u++) v[u] = (i0 + u < N_NODES) ? deg[i0 + u] : 0;
        int tsum = v[0] + v[1] + v[2] + v[3];
        int incl = tsum;
#pragma unroll
        for (int off = 1; off < 64; off <<= 1) {
            int u = __shfl_up(incl, off, 64);
            if (lane >= off) incl += u;
        }
        if (lane == 63) wsum[wave] = incl;
        __syncthreads();
        if (wave == 0) {
            int ws = (lane < 16) ? wsum[lane] : 0;
#pragma unroll
            for (int off = 1; off < 16; off <<= 1) {
                int u = __shfl_up(ws, off, 64);
                if (lane >= off) ws += u;
            }
            if (lane < 16) wsum[lane] = ws;
        }
        __syncthreads();
        int carry = carry_s;
        int chunk_total = wsum[15];
        int p = carry + ((wave == 0) ? 0 : wsum[wave - 1]) + incl - tsum;
#pragma unroll
        for (int u = 0; u < 4; u++) {
            int i = i0 + u;
            if (i < N_NODES) { cursor[i] = p; p += v[u]; row_start[i + 1] = p; }
        }
        __syncthreads();
        if (t == 0) carry_s = carry + chunk_total;
    }
}

// scatter edges into CSR order; also permute edge_attr so fused reads are coalesced
__global__ void k_scatter(const int* __restrict__ ei, const float* __restrict__ edge_attr,
                          int* __restrict__ cursor,
                          int* __restrict__ ssrc, float* __restrict__ ea_s) {
    int e = blockIdx.x * blockDim.x + threadIdx.x;
    if (e < N_EDGES) {
        int d = ei[N_EDGES + e];
        int pos = atomicAdd(&cursor[d], 1);
        ssrc[pos] = ei[e];
        const float4* s4 = (const float4*)(edge_attr + (size_t)e * EDGE_DIM);
        float4* d4 = (float4*)(ea_s + (size_t)pos * EDGE_DIM);
        d4[0] = s4[0]; d4[1] = s4[1]; d4[2] = s4[2]; d4[3] = s4[3];
    }
}

// ---------------- fused edge phase: logits + softmax + aggregate + LN --------
// one block (128 thr = 2 waves) per destination node. R7 body + asm-pinned We:
// empty inline-asm "+v" makes the 64 loaded floats opaque — the compiler
// CANNOT rematerialize them inside the edge loop (R4/R7/R8 all show it will
// re-load any pure load chain). ~100 VGPR live, no spill expected.
__global__ __launch_bounds__(128) void k_edge_fused(
    const bf16* __restrict__ xlr, const float* __restrict__ ea_s,
    const int* __restrict__ row_start, const int* __restrict__ ssrc,
    const float* __restrict__ We_l, const float* __restrict__ att_l,
    const float* __restrict__ bgat_l, const float* __restrict__ gamma_l,
    const float* __restrict__ beta_l,
    int has_res,
    const int* __restrict__ batch, float* __restrict__ hsum, int do_pool,
    bf16* __restrict__ hbf_out) {
    int n = blockIdx.x;
    int t = threadIdx.x;
    int wave = t >> 6;
    int lane = t & 63;
    int c0 = wave * 256 + lane * 4;
    int head = c0 >> 7;

    // loop-invariant We slice, pinned in VGPRs via asm barrier
    float wx[16], wy[16], wz[16], ww[16];
#pragma unroll
    for (int k = 0; k < 16; k++) {
        float4 w = *(const float4*)(We_l + k * HC + c0);
        wx[k] = w.x; wy[k] = w.y; wz[k] = w.z; ww[k] = w.w;
    }
#pragma unroll
    for (int k = 0; k < 16; k++) {
        asm volatile("" : "+v"(wx[k]), "+v"(wy[k]), "+v"(wz[k]), "+v"(ww[k]));
    }

    float4 att4 = *(const float4*)(att_l + head * HID + (c0 & 127));
    bf16x4 vr = *(const bf16x4*)(xlr + (size_t)n * NCAT + 512 + c0);
    float xr0 = (float)vr[0], xr1 = (float)vr[1], xr2 = (float)vr[2], xr3 = (float)vr[3];

    int e0 = row_start[n], e1 = row_start[n + 1];
    float l0 = 0.f, l1 = 0.f;
    float4 a0 = {0.f, 0.f, 0.f, 0.f}, a1 = {0.f, 0.f, 0.f, 0.f};

    for (int j = e0; j < e1; j++) {
        float* lsum = ((j - e0) & 1) ? &l1 : &l0;
        float4* acc = ((j - e0) & 1) ? &a1 : &a0;
        int s = ssrc[j];
        const float4* eap = (const float4*)(ea_s + (size_t)j * EDGE_DIM);
        float4 q0 = eap[0], q1 = eap[1], q2 = eap[2], q3 = eap[3];
        float eav[16] = {q0.x, q0.y, q0.z, q0.w, q1.x, q1.y, q1.z, q1.w,
                         q2.x, q2.y, q2.z, q2.w, q3.x, q3.y, q3.z, q3.w};
        bf16x4 vl = *(const bf16x4*)(xlr + (size_t)s * NCAT + c0);
        float xl0 = (float)vl[0], xl1 = (float)vl[1];
        float xl2 = (float)vl[2], xl3 = (float)vl[3];
        float e0x = 0.f, e1x = 0.f, e2x = 0.f, e3x = 0.f;
#pragma unroll
        for (int k = 0; k < 16; k++) {
            e0x = fmaf(eav[k], wx[k], e0x);
            e1x = fmaf(eav[k], wy[k], e1x);
            e2x = fmaf(eav[k], wz[k], e2x);
            e3x = fmaf(eav[k], ww[k], e3x);
        }
        float m0 = xl0 + xr0 + e0x; m0 = fmaxf(m0, 0.2f * m0);
        float m1 = xl1 + xr1 + e1x; m1 = fmaxf(m1, 0.2f * m1);
        float m2 = xl2 + xr2 + e2x; m2 = fmaxf(m2, 0.2f * m2);
        float m3 = xl3 + xr3 + e3x; m3 = fmaxf(m3, 0.2f * m3);
        float partial = m0 * att4.x + m1 * att4.y + m2 * att4.z + m3 * att4.w;
#pragma unroll
        for (int off = 1; off < 32; off <<= 1) partial += __shfl_xor(partial, off, 64);
        float p = __expf(partial);
        *lsum += p;
        acc->x = fmaf(p, xl0, acc->x);
        acc->y = fmaf(p, xl1, acc->y);
        acc->z = fmaf(p, xl2, acc->z);
        acc->w = fmaf(p, xl3, acc->w);
    }

    float inv = 1.f / (l0 + l1 + 1e-16f);

    __shared__ float sout[HC];
    __shared__ float red[4];
    sout[c0 + 0] = (a0.x + a1.x) * inv;
    sout[c0 + 1] = (a0.y + a1.y) * inv;
    sout[c0 + 2] = (a0.z + a1.z) * inv;
    sout[c0 + 3] = (a0.w + a1.w) * inv;
    __syncthreads();

    int c = t;
    float v = 0.25f * (sout[c] + sout[c + 128] + sout[c + 256] + sout[c + 384]) + bgat_l[c];
    float s1 = v, s2 = v * v;
#pragma unroll
    for (int off = 1; off < 64; off <<= 1) {
        s1 += __shfl_xor(s1, off, 64);
        s2 += __shfl_xor(s2, off, 64);
    }
    if (lane == 0) { red[wave * 2] = s1; red[wave * 2 + 1] = s2; }
    __syncthreads();
    s1 = red[0] + red[2];
    s2 = red[1] + red[3];
    float mu = s1 * (1.f / HID);
    float var = s2 * (1.f / HID) - mu * mu;
    float rstd = rsqrtf(var + 1e-5f);
    float y = fmaf(gamma_l[c] * (v - mu), rstd, beta_l[c]);
    y = elu_f(y);
    if (has_res) y += (float)xlr[(size_t)n * NCAT + 1024 + c];
    if (do_pool) atomicAdd(&hsum[(size_t)batch[n] * HID + c], y);
    else hbf_out[(size_t)n * HID + c] = (bf16)y;
}

// ---------------- MLP head ----------------
__global__ __launch_bounds__(128) void k_mlp(const float* __restrict__ hsum,
                                             const int* __restrict__ cnt,
                                             const float* __restrict__ W1, const float* __restrict__ b1,
                                             const float* __restrict__ W2, const float* __restrict__ b2,
                                             const float* __restrict__ W3, const float* __restrict__ b3,
                                             float* __restrict__ out) {
    int g = blockIdx.x, t = threadIdx.x;
    __shared__ float hg[HID], z1[HID], z2[64];
    float invc = 1.f / fmaxf((float)cnt[g], 1.f);
    hg[t] = hsum[(size_t)g * HID + t] * invc;
    __syncthreads();
    float s = b1[t];
#pragma unroll 8
    for (int k = 0; k < HID; k++) s = fmaf(hg[k], W1[k * HID + t], s);
    z1[t] = fmaxf(s, 0.f);
    __syncthreads();
    if (t < 64) {
        float s2 = b2[t];
#pragma unroll 8
        for (int k = 0; k < HID; k++) s2 = fmaf(z1[k], W2[k * 64 + t], s2);
        z2[t] = fmaxf(s2, 0.f);
    }
    __syncthreads();
    if (t < 64) {
        float s3 = z2[t] * W3[t];
#pragma unroll
        for (int off = 1; off < 64; off <<= 1) s3 += __shfl_xor(s3, off, 64);
        if (t == 0) out[g] = s3 + b3[0];
    }
}

// ---------------- host launcher ----------------
extern "C" void kernel_launch(void* const* d_in, const int* in_sizes, int n_in,
                              void* d_out, int out_size, void* d_ws, size_t ws_size,
                              hipStream_t stream) {
    const float* x         = (const float*)d_in[0];
    const int*   ei        = (const int*)  d_in[1];
    const float* edge_attr = (const float*)d_in[2];
    const int*   batch     = (const int*)  d_in[3];
    const float* Win       = (const float*)d_in[4];
    const float* b_in      = (const float*)d_in[5];
    const float* Wl        = (const float*)d_in[6];
    const float* bl        = (const float*)d_in[7];
    const float* Wr        = (const float*)d_in[8];
    const float* br        = (const float*)d_in[9];
    const float* We        = (const float*)d_in[10];
    const float* att       = (const float*)d_in[11];
    const float* b_gat     = (const float*)d_in[12];
    const float* gamma     = (const float*)d_in[13];
    const float* beta      = (const float*)d_in[14];
    const float* Wres      = (const float*)d_in[15];
    const float* bres      = (const float*)d_in[16];
    const float* W1        = (const float*)d_in[17];
    const float* b1        = (const float*)d_in[18];
    const float* W2        = (const float*)d_in[19];
    const float* b2        = (const float*)d_in[20];
    const float* W3        = (const float*)d_in[21];
    const float* b3        = (const float*)d_in[22];
    float* out = (float*)d_out;

    char* ws = (char*)d_ws;
    size_t off = 0;
    auto alloc = [&](size_t bytes) -> void* {
        void* p = ws + off;
        off = (off + bytes + 255) & ~(size_t)255;
        return p;
    };
    bf16*  h_bf    = (bf16*) alloc((size_t)N_NODES * HID * 2);
    bf16*  xlr     = (bf16*) alloc((size_t)N_NODES * NCAT * 2);
    bf16*  WT      = (bf16*) alloc((size_t)LAYERS * NCAT * HID * 2);
    float* bcat    = (float*)alloc((size_t)LAYERS * NCAT * 4);
    float* ea_s    = (float*)alloc((size_t)N_EDGES * EDGE_DIM * 4);
    // contiguous zero region: [hsum | cnt | deg]
    char*  zbase   = ws + off;
    float* hsum    = (float*)alloc((size_t)NUM_GRAPHS * HID * 4);
    int*   cnt     = (int*)  alloc((size_t)NUM_GRAPHS * 4);
    int*   deg     = (int*)  alloc((size_t)N_NODES * 4);
    size_t zlen    = (size_t)((ws + off) - zbase);
    int*   rowst   = (int*)  alloc((size_t)(N_NODES + 1) * 4);
    int*   cursor  = (int*)  alloc((size_t)N_NODES * 4);
    int*   ssrc    = (int*)  alloc((size_t)N_EDGES * 4);
    (void)ws_size; // requires ~36 MB

    hipMemsetAsync(zbase, 0, zlen, stream);

    k_prep_w<<<dim3(9, LAYERS, 8), 128, 0, stream>>>(Wl, bl, Wr, br, Wres, bres, WT, bcat);
    k_degree<<<(N_EDGES + 255) / 256, 256, 0, stream>>>(ei, batch, deg, cnt);
    k_scan<<<1, 1024, 0, stream>>>(deg, rowst, cursor);
    k_scatter<<<(N_EDGES + 255) / 256, 256, 0, stream>>>(ei, edge_attr, cursor, ssrc, ea_s);
    k_init_h<<<N_NODES, 128, 0, stream>>>(x, Win, b_in, h_bf);

    const int MG = (N_NODES + 127) / 128;  // 79
    for (int i = 0; i < LAYERS; i++) {
        int ntiles = (i > 0) ? (NCAT / 128) : (1024 / 128);
        k_gemm_mfma<<<dim3(MG, ntiles), 256, 0, stream>>>(
            h_bf, WT + (size_t)i * NCAT * HID, bcat + (size_t)i * NCAT, xlr, N_NODES);
        k_edge_fused<<<N_NODES, 128, 0, stream>>>(
            xlr, ea_s, rowst, ssrc,
            We + (size_t)i * EDGE_DIM * HC, att + (size_t)i * HEADS * HID,
            b_gat + (size_t)i * HID, gamma + (size_t)i * HID, beta + (size_t)i * HID,
            (i > 0) ? 1 : 0,
            batch, hsum, (i == LAYERS - 1) ? 1 : 0, h_bf);
    }

    k_mlp<<<NUM_GRAPHS, 128, 0, stream>>>(hsum, cnt, W1, b1, W2, b2, W3, b3, out);
}

// Round 10
// 419.502 us; speedup vs baseline: 1.1211x; 1.1211x over previous
//
#include <hip/hip_runtime.h>

#define N_NODES 10000
#define N_EDGES 100000
#define IN_CH 64
#define EDGE_DIM 16
#define HID 128
#define HEADS 4
#define HC 512          // HEADS*HID
#define LAYERS 4
#define NUM_GRAPHS 256
#define NCAT 1152       // 512(xl) + 512(xr) + 128(res) packed cols
#define LDP 136         // padded LDS stride (bf16 elems)

typedef __bf16 bf16;
typedef __bf16 bf16x8 __attribute__((ext_vector_type(8)));
typedef __bf16 bf16x4 __attribute__((ext_vector_type(4)));
typedef float floatx4 __attribute__((ext_vector_type(4)));
typedef _Float16 f16;
typedef _Float16 f16x2 __attribute__((ext_vector_type(2)));

__device__ __forceinline__ float elu_f(float x) { return x > 0.f ? x : (__expf(x) - 1.f); }

// ---------------- weight prep ----------------
// nt 0-8: WT[l][n][k] bf16 via LDS transpose (GEMM B operand).
// nt 9:   WeH[l][c][k] f16 (transposed We for the edge kernel).
__global__ __launch_bounds__(128) void k_prep_w(
    const float* __restrict__ Wl, const float* __restrict__ bl,
    const float* __restrict__ Wr, const float* __restrict__ br,
    const float* __restrict__ Wres, const float* __restrict__ bres,
    const float* __restrict__ We,
    bf16* __restrict__ WT, float* __restrict__ bcat, f16* __restrict__ WeH) {
    __shared__ float tile[16][129];
    int nt = blockIdx.x, i = blockIdx.y, z = blockIdx.z;
    int t = threadIdx.x;
    if (nt == 9) {
        if (z < 4) {
            int c = z * 128 + t;
            const float* src = We + (size_t)i * EDGE_DIM * HC + c;
            f16 buf[16];
#pragma unroll
            for (int k = 0; k < EDGE_DIM; k++) buf[k] = (f16)src[(size_t)k * HC];
            f16* dst = WeH + ((size_t)i * HC + c) * EDGE_DIM;
            *(uint4*)dst = *(uint4*)buf;
            *(uint4*)(dst + 8) = *(uint4*)(buf + 8);
        }
        return;
    }
    int n0 = nt * 128;
    const float* base = nullptr; const float* bsrc = nullptr; int ld = 0;
    if (nt < 4)       { base = Wl + (size_t)i * HID * HC + n0;            bsrc = bl + i * HC + n0;              ld = HC; }
    else if (nt < 8)  { base = Wr + (size_t)i * HID * HC + (n0 - 512);    bsrc = br + i * HC + (n0 - 512);      ld = HC; }
    else if (i > 0)   { base = Wres + (size_t)(i - 1) * HID * HID;        bsrc = bres + (size_t)(i - 1) * HID;  ld = HID; }
    if (base) {
#pragma unroll
        for (int r = 0; r < 16; r++) tile[r][t] = base[(size_t)(z * 16 + r) * ld + t];
    } else {
#pragma unroll
        for (int r = 0; r < 16; r++) tile[r][t] = 0.f;
    }
    __syncthreads();
    int n = n0 + t;
    if (z == 0) bcat[(size_t)i * NCAT + n] = base ? bsrc[t] : 0.f;
    bf16* dst = WT + ((size_t)i * NCAT + n) * HID + z * 16;
#pragma unroll
    for (int kc = 0; kc < 2; kc++) {
        bf16x8 v;
#pragma unroll
        for (int u = 0; u < 8; u++) v[u] = (bf16)tile[kc * 8 + u][t];
        *(bf16x8*)(dst + kc * 8) = v;
    }
}

// ---------------- h0 = elu(x @ Win + b_in) ----------------
__global__ __launch_bounds__(128) void k_init_h(const float* __restrict__ x,
                                                const float* __restrict__ Win,
                                                const float* __restrict__ b_in,
                                                bf16* __restrict__ h_bf) {
    __shared__ float xs[IN_CH];
    int n = blockIdx.x, t = threadIdx.x;
    if (t < IN_CH) xs[t] = x[(size_t)n * IN_CH + t];
    __syncthreads();
    float s = b_in[t];
#pragma unroll 8
    for (int k = 0; k < IN_CH; k++) s = fmaf(xs[k], Win[k * HID + t], s);
    h_bf[(size_t)n * HID + t] = (bf16)elu_f(s);
}

// ---------------- MFMA bf16 GEMM: C[M,NCAT] = A[M,128] @ WT^T + bias ------
__global__ __launch_bounds__(256, 2) void k_gemm_mfma(
    const bf16* __restrict__ A, const bf16* __restrict__ WT,
    const float* __restrict__ bcat, bf16* __restrict__ C, int M) {
    __shared__ __align__(16) unsigned short As[128 * LDP];
    __shared__ __align__(16) unsigned short Bs[128 * LDP];
    int t = threadIdx.x;
    int r0 = blockIdx.x * 128, c0 = blockIdx.y * 128;
#pragma unroll
    for (int i = 0; i < 8; i++) {
        int idx = t + i * 256;
        int row = idx >> 4;
        int ch = idx & 15;
        int r = r0 + row; if (r >= M) r = M - 1;
        uint4 va = *(const uint4*)(A + (size_t)r * HID + ch * 8);
        *(uint4*)&As[row * LDP + ch * 8] = va;
        uint4 vb = *(const uint4*)(WT + (size_t)(c0 + row) * HID + ch * 8);
        *(uint4*)&Bs[row * LDP + ch * 8] = vb;
    }
    __syncthreads();

    int wave = t >> 6, lane = t & 63;
    int wm = wave & 1, wn = wave >> 1;
    int quad = lane >> 4, lm = lane & 15;
    floatx4 zero = {0.f, 0.f, 0.f, 0.f};
    floatx4 acc[4][4];
#pragma unroll
    for (int mi = 0; mi < 4; mi++)
#pragma unroll
        for (int ni = 0; ni < 4; ni++) acc[mi][ni] = zero;

    const unsigned short* Ab = &As[(wm * 64 + lm) * LDP + quad * 8];
    const unsigned short* Bb = &Bs[(wn * 64 + lm) * LDP + quad * 8];
#pragma unroll
    for (int ks = 0; ks < 4; ks++) {
        bf16x8 af[4], bfr[4];
#pragma unroll
        for (int mi = 0; mi < 4; mi++) af[mi] = *(const bf16x8*)(Ab + mi * 16 * LDP + ks * 32);
#pragma unroll
        for (int ni = 0; ni < 4; ni++) bfr[ni] = *(const bf16x8*)(Bb + ni * 16 * LDP + ks * 32);
#pragma unroll
        for (int mi = 0; mi < 4; mi++)
#pragma unroll
            for (int ni = 0; ni < 4; ni++)
                acc[mi][ni] = __builtin_amdgcn_mfma_f32_16x16x32_bf16(bfr[ni], af[mi], acc[mi][ni], 0, 0, 0);
    }

#pragma unroll
    for (int mi = 0; mi < 4; mi++) {
        int row = r0 + wm * 64 + mi * 16 + lm;
        if (row < M) {
            bf16* crow = C + (size_t)row * NCAT;
#pragma unroll
            for (int ni = 0; ni < 4; ni++) {
                int cb = c0 + wn * 64 + ni * 16 + quad * 4;
                float4 b4 = *(const float4*)(bcat + cb);
                floatx4 v = acc[mi][ni];
                bf16x4 o = {(bf16)(v[0] + b4.x), (bf16)(v[1] + b4.y),
                            (bf16)(v[2] + b4.z), (bf16)(v[3] + b4.w)};
                *(bf16x4*)(crow + cb) = o;
            }
        }
    }
}

// ---------------- CSR build (+ per-graph node counts folded in) ----------------
__global__ void k_degree(const int* __restrict__ ei, const int* __restrict__ batch,
                         int* __restrict__ deg, int* __restrict__ cnt) {
    int e = blockIdx.x * blockDim.x + threadIdx.x;
    if (e < N_EDGES) atomicAdd(&deg[ei[N_EDGES + e]], 1);
    if (e < N_NODES) atomicAdd(&cnt[batch[e]], 1);
}

// shfl-based scan, 4 elems/thread
__global__ __launch_bounds__(1024) void k_scan(const int* __restrict__ deg,
                                               int* __restrict__ row_start,
                                               int* __restrict__ cursor) {
    __shared__ int wsum[16];
    __shared__ int carry_s;
    int t = threadIdx.x;
    int wave = t >> 6, lane = t & 63;
    if (t == 0) { carry_s = 0; row_start[0] = 0; }
    __syncthreads();
    for (int base = 0; base < N_NODES; base += 4096) {
        int i0 = base + t * 4;
        int v[4];
#pragma unroll
        for (int u = 0; u < 4; u++) v[u] = (i0 + u < N_NODES) ? deg[i0 + u] : 0;
        int tsum = v[0] + v[1] + v[2] + v[3];
        int incl = tsum;
#pragma unroll
        for (int off = 1; off < 64; off <<= 1) {
            int u = __shfl_up(incl, off, 64);
            if (lane >= off) incl += u;
        }
        if (lane == 63) wsum[wave] = incl;
        __syncthreads();
        if (wave == 0) {
            int ws = (lane < 16) ? wsum[lane] : 0;
#pragma unroll
            for (int off = 1; off < 16; off <<= 1) {
                int u = __shfl_up(ws, off, 64);
                if (lane >= off) ws += u;
            }
            if (lane < 16) wsum[lane] = ws;
        }
        __syncthreads();
        int carry = carry_s;
        int chunk_total = wsum[15];
        int p = carry + ((wave == 0) ? 0 : wsum[wave - 1]) + incl - tsum;
#pragma unroll
        for (int u = 0; u < 4; u++) {
            int i = i0 + u;
            if (i < N_NODES) { cursor[i] = p; p += v[u]; row_start[i + 1] = p; }
        }
        __syncthreads();
        if (t == 0) carry_s = carry + chunk_total;
    }
}

// scatter edges into CSR order; permute + f16-convert edge_attr
__global__ void k_scatter(const int* __restrict__ ei, const float* __restrict__ edge_attr,
                          int* __restrict__ cursor,
                          int* __restrict__ ssrc, f16* __restrict__ ea_h) {
    int e = blockIdx.x * blockDim.x + threadIdx.x;
    if (e < N_EDGES) {
        int d = ei[N_EDGES + e];
        int pos = atomicAdd(&cursor[d], 1);
        ssrc[pos] = ei[e];
        const float* s = edge_attr + (size_t)e * EDGE_DIM;
        f16 buf[16];
#pragma unroll
        for (int q = 0; q < 16; q++) buf[q] = (f16)s[q];
        f16* dst = ea_h + (size_t)pos * EDGE_DIM;
        *(uint4*)dst = *(uint4*)buf;
        *(uint4*)(dst + 8) = *(uint4*)(buf + 8);
    }
}

// ---------------- fused edge phase: logits + softmax + aggregate + LN --------
// one block (128 thr = 2 waves) per destination node. We slice is 128
// CONTIGUOUS bytes of f16 (WeH[c][k] transposed layout) -> even when the
// compiler rematerializes it per edge it's 2 dwordx4 loads, not 16 float4.
// ea_h f16 = 2 more loads. v_dot2_f32_f16 halves the matvec VALU.
__global__ __launch_bounds__(128) void k_edge_fused(
    const bf16* __restrict__ xlr, const f16* __restrict__ ea_h,
    const int* __restrict__ row_start, const int* __restrict__ ssrc,
    const f16* __restrict__ WeH_l, const float* __restrict__ att_l,
    const float* __restrict__ bgat_l, const float* __restrict__ gamma_l,
    const float* __restrict__ beta_l,
    int has_res,
    const int* __restrict__ batch, float* __restrict__ hsum, int do_pool,
    bf16* __restrict__ hbf_out) {
    int n = blockIdx.x;
    int t = threadIdx.x;
    int wave = t >> 6;
    int lane = t & 63;
    int c0 = wave * 256 + lane * 4;
    int head = c0 >> 7;

    const f16x2* wr = (const f16x2*)(WeH_l + (size_t)c0 * EDGE_DIM); // 32 pairs, 128B contiguous
    float4 att4 = *(const float4*)(att_l + head * HID + (c0 & 127));
    bf16x4 vr = *(const bf16x4*)(xlr + (size_t)n * NCAT + 512 + c0);
    float xr0 = (float)vr[0], xr1 = (float)vr[1], xr2 = (float)vr[2], xr3 = (float)vr[3];

    int e0 = row_start[n], e1 = row_start[n + 1];
    float lsum = 0.f;
    float4 acc = {0.f, 0.f, 0.f, 0.f};

    for (int j = e0; j < e1; j++) {
        int s = ssrc[j];
        const f16x2* eah = (const f16x2*)(ea_h + (size_t)j * EDGE_DIM);
        f16x2 ep[8];
#pragma unroll
        for (int kp = 0; kp < 8; kp++) ep[kp] = eah[kp];
        bf16x4 vl = *(const bf16x4*)(xlr + (size_t)s * NCAT + c0);
        float xl0 = (float)vl[0], xl1 = (float)vl[1];
        float xl2 = (float)vl[2], xl3 = (float)vl[3];
        float ec0 = 0.f, ec1 = 0.f, ec2 = 0.f, ec3 = 0.f;
#pragma unroll
        for (int kp = 0; kp < 8; kp++) {
            ec0 = __builtin_amdgcn_fdot2(wr[kp],      ep[kp], ec0, false);
            ec1 = __builtin_amdgcn_fdot2(wr[8 + kp],  ep[kp], ec1, false);
            ec2 = __builtin_amdgcn_fdot2(wr[16 + kp], ep[kp], ec2, false);
            ec3 = __builtin_amdgcn_fdot2(wr[24 + kp], ep[kp], ec3, false);
        }
        float m0 = xl0 + xr0 + ec0; m0 = fmaxf(m0, 0.2f * m0);
        float m1 = xl1 + xr1 + ec1; m1 = fmaxf(m1, 0.2f * m1);
        float m2 = xl2 + xr2 + ec2; m2 = fmaxf(m2, 0.2f * m2);
        float m3 = xl3 + xr3 + ec3; m3 = fmaxf(m3, 0.2f * m3);
        float partial = m0 * att4.x + m1 * att4.y + m2 * att4.z + m3 * att4.w;
#pragma unroll
        for (int off = 1; off < 32; off <<= 1) partial += __shfl_xor(partial, off, 64);
        float p = __expf(partial);
        lsum += p;
        acc.x = fmaf(p, xl0, acc.x);
        acc.y = fmaf(p, xl1, acc.y);
        acc.z = fmaf(p, xl2, acc.z);
        acc.w = fmaf(p, xl3, acc.w);
    }

    float inv = 1.f / (lsum + 1e-16f);

    __shared__ float sout[HC];
    __shared__ float red[4];
    sout[c0 + 0] = acc.x * inv;
    sout[c0 + 1] = acc.y * inv;
    sout[c0 + 2] = acc.z * inv;
    sout[c0 + 3] = acc.w * inv;
    __syncthreads();

    int c = t;
    float v = 0.25f * (sout[c] + sout[c + 128] + sout[c + 256] + sout[c + 384]) + bgat_l[c];
    float s1 = v, s2 = v * v;
#pragma unroll
    for (int off = 1; off < 64; off <<= 1) {
        s1 += __shfl_xor(s1, off, 64);
        s2 += __shfl_xor(s2, off, 64);
    }
    if (lane == 0) { red[wave * 2] = s1; red[wave * 2 + 1] = s2; }
    __syncthreads();
    s1 = red[0] + red[2];
    s2 = red[1] + red[3];
    float mu = s1 * (1.f / HID);
    float var = s2 * (1.f / HID) - mu * mu;
    float rstd = rsqrtf(var + 1e-5f);
    float y = fmaf(gamma_l[c] * (v - mu), rstd, beta_l[c]);
    y = elu_f(y);
    if (has_res) y += (float)xlr[(size_t)n * NCAT + 1024 + c];
    if (do_pool) atomicAdd(&hsum[(size_t)batch[n] * HID + c], y);
    else hbf_out[(size_t)n * HID + c] = (bf16)y;
}

// ---------------- MLP head ----------------
__global__ __launch_bounds__(128) void k_mlp(const float* __restrict__ hsum,
                                             const int* __restrict__ cnt,
                                             const float* __restrict__ W1, const float* __restrict__ b1,
                                             const float* __restrict__ W2, const float* __restrict__ b2,
                                             const float* __restrict__ W3, const float* __restrict__ b3,
                                             float* __restrict__ out) {
    int g = blockIdx.x, t = threadIdx.x;
    __shared__ float hg[HID], z1[HID], z2[64];
    float invc = 1.f / fmaxf((float)cnt[g], 1.f);
    hg[t] = hsum[(size_t)g * HID + t] * invc;
    __syncthreads();
    float s = b1[t];
#pragma unroll 8
    for (int k = 0; k < HID; k++) s = fmaf(hg[k], W1[k * HID + t], s);
    z1[t] = fmaxf(s, 0.f);
    __syncthreads();
    if (t < 64) {
        float s2 = b2[t];
#pragma unroll 8
        for (int k = 0; k < HID; k++) s2 = fmaf(z1[k], W2[k * 64 + t], s2);
        z2[t] = fmaxf(s2, 0.f);
    }
    __syncthreads();
    if (t < 64) {
        float s3 = z2[t] * W3[t];
#pragma unroll
        for (int off = 1; off < 64; off <<= 1) s3 += __shfl_xor(s3, off, 64);
        if (t == 0) out[g] = s3 + b3[0];
    }
}

// ---------------- host launcher ----------------
extern "C" void kernel_launch(void* const* d_in, const int* in_sizes, int n_in,
                              void* d_out, int out_size, void* d_ws, size_t ws_size,
                              hipStream_t stream) {
    const float* x         = (const float*)d_in[0];
    const int*   ei        = (const int*)  d_in[1];
    const float* edge_attr = (const float*)d_in[2];
    const int*   batch     = (const int*)  d_in[3];
    const float* Win       = (const float*)d_in[4];
    const float* b_in      = (const float*)d_in[5];
    const float* Wl        = (const float*)d_in[6];
    const float* bl        = (const float*)d_in[7];
    const float* Wr        = (const float*)d_in[8];
    const float* br        = (const float*)d_in[9];
    const float* We        = (const float*)d_in[10];
    const float* att       = (const float*)d_in[11];
    const float* b_gat     = (const float*)d_in[12];
    const float* gamma     = (const float*)d_in[13];
    const float* beta      = (const float*)d_in[14];
    const float* Wres      = (const float*)d_in[15];
    const float* bres      = (const float*)d_in[16];
    const float* W1        = (const float*)d_in[17];
    const float* b1        = (const float*)d_in[18];
    const float* W2        = (const float*)d_in[19];
    const float* b2        = (const float*)d_in[20];
    const float* W3        = (const float*)d_in[21];
    const float* b3        = (const float*)d_in[22];
    float* out = (float*)d_out;

    char* ws = (char*)d_ws;
    size_t off = 0;
    auto alloc = [&](size_t bytes) -> void* {
        void* p = ws + off;
        off = (off + bytes + 255) & ~(size_t)255;
        return p;
    };
    bf16*  h_bf    = (bf16*) alloc((size_t)N_NODES * HID * 2);
    bf16*  xlr     = (bf16*) alloc((size_t)N_NODES * NCAT * 2);
    bf16*  WT      = (bf16*) alloc((size_t)LAYERS * NCAT * HID * 2);
    float* bcat    = (float*)alloc((size_t)LAYERS * NCAT * 4);
    f16*   WeH     = (f16*)  alloc((size_t)LAYERS * HC * EDGE_DIM * 2);
    f16*   ea_h    = (f16*)  alloc((size_t)N_EDGES * EDGE_DIM * 2);
    // contiguous zero region: [hsum | cnt | deg]
    char*  zbase   = ws + off;
    float* hsum    = (float*)alloc((size_t)NUM_GRAPHS * HID * 4);
    int*   cnt     = (int*)  alloc((size_t)NUM_GRAPHS * 4);
    int*   deg     = (int*)  alloc((size_t)N_NODES * 4);
    size_t zlen    = (size_t)((ws + off) - zbase);
    int*   rowst   = (int*)  alloc((size_t)(N_NODES + 1) * 4);
    int*   cursor  = (int*)  alloc((size_t)N_NODES * 4);
    int*   ssrc    = (int*)  alloc((size_t)N_EDGES * 4);
    (void)ws_size; // requires ~33 MB

    hipMemsetAsync(zbase, 0, zlen, stream);

    k_prep_w<<<dim3(10, LAYERS, 8), 128, 0, stream>>>(Wl, bl, Wr, br, Wres, bres, We,
                                                      WT, bcat, WeH);
    k_degree<<<(N_EDGES + 255) / 256, 256, 0, stream>>>(ei, batch, deg, cnt);
    k_scan<<<1, 1024, 0, stream>>>(deg, rowst, cursor);
    k_scatter<<<(N_EDGES + 255) / 256, 256, 0, stream>>>(ei, edge_attr, cursor, ssrc, ea_h);
    k_init_h<<<N_NODES, 128, 0, stream>>>(x, Win, b_in, h_bf);

    const int MG = (N_NODES + 127) / 128;  // 79
    for (int i = 0; i < LAYERS; i++) {
        int ntiles = (i > 0) ? (NCAT / 128) : (1024 / 128);
        k_gemm_mfma<<<dim3(MG, ntiles), 256, 0, stream>>>(
            h_bf, WT + (size_t)i * NCAT * HID, bcat + (size_t)i * NCAT, xlr, N_NODES);
        k_edge_fused<<<N_NODES, 128, 0, stream>>>(
            xlr, ea_h, rowst, ssrc,
            WeH + (size_t)i * HC * EDGE_DIM, att + (size_t)i * HEADS * HID,
            b_gat + (size_t)i * HID, gamma + (size_t)i * HID, beta + (size_t)i * HID,
            (i > 0) ? 1 : 0,
            batch, hsum, (i == LAYERS - 1) ? 1 : 0, h_bf);
    }

    k_mlp<<<NUM_GRAPHS, 128, 0, stream>>>(hsum, cnt, W1, b1, W2, b2, W3, b3, out);
}

// Round 11
// 409.131 us; speedup vs baseline: 1.1495x; 1.0253x over previous
//
#include <hip/hip_runtime.h>

#define N_NODES 10000
#define N_EDGES 100000
#define IN_CH 64
#define EDGE_DIM 16
#define HID 128
#define HEADS 4
#define HC 512          // HEADS*HID
#define LAYERS 4
#define NUM_GRAPHS 256
#define NCAT 1152       // 512(xl) + 512(xr) + 128(res) packed cols
#define LDPK 72         // padded LDS stride for 64-elem K-chunk (bf16 elems)

#define PREP_BLOCKS 320 // 10 * LAYERS * 8
#define DEG_BLOCKS 782  // ceil(N_EDGES/128)

typedef __bf16 bf16;
typedef __bf16 bf16x8 __attribute__((ext_vector_type(8)));
typedef __bf16 bf16x4 __attribute__((ext_vector_type(4)));
typedef float floatx4 __attribute__((ext_vector_type(4)));
typedef _Float16 f16;
typedef _Float16 f16x2 __attribute__((ext_vector_type(2)));

__device__ __forceinline__ float elu_f(float x) { return x > 0.f ? x : (__expf(x) - 1.f); }

// ---------------- merged prep: weight repack + degree/count + h0 ----------------
// blocks [0,320): WT/WeH/bcat repack; [320,1102): degree+graph counts;
// [1102,11102): h0 = elu(x @ Win + b_in). All independent work, one dispatch.
__global__ __launch_bounds__(128) void k_prep_all(
    const float* __restrict__ Wl, const float* __restrict__ bl,
    const float* __restrict__ Wr, const float* __restrict__ br,
    const float* __restrict__ Wres, const float* __restrict__ bres,
    const float* __restrict__ We,
    bf16* __restrict__ WT, float* __restrict__ bcat, f16* __restrict__ WeH,
    const int* __restrict__ ei, const int* __restrict__ batch,
    int* __restrict__ deg, int* __restrict__ cnt,
    const float* __restrict__ x, const float* __restrict__ Win,
    const float* __restrict__ b_in, bf16* __restrict__ h_bf) {
    __shared__ float smem[16 * 129];
    int b = blockIdx.x;
    int t = threadIdx.x;

    if (b < PREP_BLOCKS) {
        int nt = b % 10, i = (b / 10) % LAYERS, z = b / 40;
        if (nt == 9) {
            if (z < 4) {
                int c = z * 128 + t;
                const float* src = We + (size_t)i * EDGE_DIM * HC + c;
                f16 buf[16];
#pragma unroll
                for (int k = 0; k < EDGE_DIM; k++) buf[k] = (f16)src[(size_t)k * HC];
                f16* dst = WeH + ((size_t)i * HC + c) * EDGE_DIM;
                *(uint4*)dst = *(uint4*)buf;
                *(uint4*)(dst + 8) = *(uint4*)(buf + 8);
            }
            return;
        }
        float (*tile)[129] = (float(*)[129])smem;
        int n0 = nt * 128;
        const float* base = nullptr; const float* bsrc = nullptr; int ld = 0;
        if (nt < 4)       { base = Wl + (size_t)i * HID * HC + n0;          bsrc = bl + i * HC + n0;              ld = HC; }
        else if (nt < 8)  { base = Wr + (size_t)i * HID * HC + (n0 - 512);  bsrc = br + i * HC + (n0 - 512);      ld = HC; }
        else if (i > 0)   { base = Wres + (size_t)(i - 1) * HID * HID;      bsrc = bres + (size_t)(i - 1) * HID;  ld = HID; }
        if (base) {
#pragma unroll
            for (int r = 0; r < 16; r++) tile[r][t] = base[(size_t)(z * 16 + r) * ld + t];
        } else {
#pragma unroll
            for (int r = 0; r < 16; r++) tile[r][t] = 0.f;
        }
        __syncthreads();
        int n = n0 + t;
        if (z == 0) bcat[(size_t)i * NCAT + n] = base ? bsrc[t] : 0.f;
        bf16* dst = WT + ((size_t)i * NCAT + n) * HID + z * 16;
#pragma unroll
        for (int kc = 0; kc < 2; kc++) {
            bf16x8 v;
#pragma unroll
            for (int u = 0; u < 8; u++) v[u] = (bf16)tile[kc * 8 + u][t];
            *(bf16x8*)(dst + kc * 8) = v;
        }
    } else if (b < PREP_BLOCKS + DEG_BLOCKS) {
        int e = (b - PREP_BLOCKS) * 128 + t;
        if (e < N_EDGES) atomicAdd(&deg[ei[N_EDGES + e]], 1);
        if (e < N_NODES) atomicAdd(&cnt[batch[e]], 1);
    } else {
        int n = b - (PREP_BLOCKS + DEG_BLOCKS);
        float* xs = smem;
        if (t < IN_CH) xs[t] = x[(size_t)n * IN_CH + t];
        __syncthreads();
        float s = b_in[t];
#pragma unroll 8
        for (int k = 0; k < IN_CH; k++) s = fmaf(xs[k], Win[k * HID + t], s);
        h_bf[(size_t)n * HID + t] = (bf16)elu_f(s);
    }
}

// ---------------- MFMA bf16 GEMM: C[M,NCAT] = A[M,128] @ WT^T + bias ------
// split-K: two 64-wide chunks staged in 36.9 KB LDS -> ~4 resident blocks/CU
// (vs 2 with whole-K 69.6 KB). operand-swapped mfma: 8B vector C stores.
__global__ __launch_bounds__(256) void k_gemm_mfma(
    const bf16* __restrict__ A, const bf16* __restrict__ WT,
    const float* __restrict__ bcat, bf16* __restrict__ C, int M) {
    __shared__ __align__(16) unsigned short As[128 * LDPK];
    __shared__ __align__(16) unsigned short Bs[128 * LDPK];
    int t = threadIdx.x;
    int r0 = blockIdx.x * 128, c0 = blockIdx.y * 128;

    int wave = t >> 6, lane = t & 63;
    int wm = wave & 1, wn = wave >> 1;
    int quad = lane >> 4, lm = lane & 15;
    floatx4 zero = {0.f, 0.f, 0.f, 0.f};
    floatx4 acc[4][4];
#pragma unroll
    for (int mi = 0; mi < 4; mi++)
#pragma unroll
        for (int ni = 0; ni < 4; ni++) acc[mi][ni] = zero;

    const unsigned short* Ab = &As[(wm * 64 + lm) * LDPK + quad * 8];
    const unsigned short* Bb = &Bs[(wn * 64 + lm) * LDPK + quad * 8];

    for (int kc = 0; kc < 2; kc++) {
#pragma unroll
        for (int i = 0; i < 4; i++) {
            int idx = t + i * 256;       // 0..1023
            int row = idx >> 3;          // 0..127
            int ch = idx & 7;            // 16B chunk within 64-elem K slice
            int r = r0 + row; if (r >= M) r = M - 1;
            *(uint4*)&As[row * LDPK + ch * 8] =
                *(const uint4*)(A + (size_t)r * HID + kc * 64 + ch * 8);
            *(uint4*)&Bs[row * LDPK + ch * 8] =
                *(const uint4*)(WT + (size_t)(c0 + row) * HID + kc * 64 + ch * 8);
        }
        __syncthreads();
#pragma unroll
        for (int ks = 0; ks < 2; ks++) {
            bf16x8 af[4], bfr[4];
#pragma unroll
            for (int mi = 0; mi < 4; mi++) af[mi] = *(const bf16x8*)(Ab + mi * 16 * LDPK + ks * 32);
#pragma unroll
            for (int ni = 0; ni < 4; ni++) bfr[ni] = *(const bf16x8*)(Bb + ni * 16 * LDPK + ks * 32);
#pragma unroll
            for (int mi = 0; mi < 4; mi++)
#pragma unroll
                for (int ni = 0; ni < 4; ni++)
                    acc[mi][ni] = __builtin_amdgcn_mfma_f32_16x16x32_bf16(bfr[ni], af[mi], acc[mi][ni], 0, 0, 0);
        }
        __syncthreads();
    }

#pragma unroll
    for (int mi = 0; mi < 4; mi++) {
        int row = r0 + wm * 64 + mi * 16 + lm;
        if (row < M) {
            bf16* crow = C + (size_t)row * NCAT;
#pragma unroll
            for (int ni = 0; ni < 4; ni++) {
                int cb = c0 + wn * 64 + ni * 16 + quad * 4;
                float4 b4 = *(const float4*)(bcat + cb);
                floatx4 v = acc[mi][ni];
                bf16x4 o = {(bf16)(v[0] + b4.x), (bf16)(v[1] + b4.y),
                            (bf16)(v[2] + b4.z), (bf16)(v[3] + b4.w)};
                *(bf16x4*)(crow + cb) = o;
            }
        }
    }
}

// shfl-based scan, 4 elems/thread
__global__ __launch_bounds__(1024) void k_scan(const int* __restrict__ deg,
                                               int* __restrict__ row_start,
                                               int* __restrict__ cursor) {
    __shared__ int wsum[16];
    __shared__ int carry_s;
    int t = threadIdx.x;
    int wave = t >> 6, lane = t & 63;
    if (t == 0) { carry_s = 0; row_start[0] = 0; }
    __syncthreads();
    for (int base = 0; base < N_NODES; base += 4096) {
        int i0 = base + t * 4;
        int v[4];
#pragma unroll
        for (int u = 0; u < 4; u++) v[u] = (i0 + u < N_NODES) ? deg[i0 + u] : 0;
        int tsum = v[0] + v[1] + v[2] + v[3];
        int incl = tsum;
#pragma unroll
        for (int off = 1; off < 64; off <<= 1) {
            int u = __shfl_up(incl, off, 64);
            if (lane >= off) incl += u;
        }
        if (lane == 63) wsum[wave] = incl;
        __syncthreads();
        if (wave == 0) {
            int ws = (lane < 16) ? wsum[lane] : 0;
#pragma unroll
            for (int off = 1; off < 16; off <<= 1) {
                int u = __shfl_up(ws, off, 64);
                if (lane >= off) ws += u;
            }
            if (lane < 16) wsum[lane] = ws;
        }
        __syncthreads();
        int carry = carry_s;
        int chunk_total = wsum[15];
        int p = carry + ((wave == 0) ? 0 : wsum[wave - 1]) + incl - tsum;
#pragma unroll
        for (int u = 0; u < 4; u++) {
            int i = i0 + u;
            if (i < N_NODES) { cursor[i] = p; p += v[u]; row_start[i + 1] = p; }
        }
        __syncthreads();
        if (t == 0) carry_s = carry + chunk_total;
    }
}

// scatter edges into CSR order; permute + f16-convert edge_attr
__global__ void k_scatter(const int* __restrict__ ei, const float* __restrict__ edge_attr,
                          int* __restrict__ cursor,
                          int* __restrict__ ssrc, f16* __restrict__ ea_h) {
    int e = blockIdx.x * blockDim.x + threadIdx.x;
    if (e < N_EDGES) {
        int d = ei[N_EDGES + e];
        int pos = atomicAdd(&cursor[d], 1);
        ssrc[pos] = ei[e];
        const float* s = edge_attr + (size_t)e * EDGE_DIM;
        f16 buf[16];
#pragma unroll
        for (int q = 0; q < 16; q++) buf[q] = (f16)s[q];
        f16* dst = ea_h + (size_t)pos * EDGE_DIM;
        *(uint4*)dst = *(uint4*)buf;
        *(uint4*)(dst + 8) = *(uint4*)(buf + 8);
    }
}

// ---------------- fused edge phase: logits + softmax + aggregate + LN --------
// one block (2 waves) per destination node. f16 We/ea (cheap remat: 2 dwordx4
// each) + unroll-2 with DUAL independent (l,acc) chains: both edges' loads
// issue together, two dot2 chains fill the VALU (R10 had 1 chain, 46% duty).
__global__ __launch_bounds__(128) void k_edge_fused(
    const bf16* __restrict__ xlr, const f16* __restrict__ ea_h,
    const int* __restrict__ row_start, const int* __restrict__ ssrc,
    const f16* __restrict__ WeH_l, const float* __restrict__ att_l,
    const float* __restrict__ bgat_l, const float* __restrict__ gamma_l,
    const float* __restrict__ beta_l,
    int has_res,
    const int* __restrict__ batch, float* __restrict__ hsum, int do_pool,
    bf16* __restrict__ hbf_out) {
    int n = blockIdx.x;
    int t = threadIdx.x;
    int wave = t >> 6;
    int lane = t & 63;
    int c0 = wave * 256 + lane * 4;
    int head = c0 >> 7;

    const f16x2* wr = (const f16x2*)(WeH_l + (size_t)c0 * EDGE_DIM); // 128B contiguous
    float4 att4 = *(const float4*)(att_l + head * HID + (c0 & 127));
    bf16x4 vr = *(const bf16x4*)(xlr + (size_t)n * NCAT + 512 + c0);
    float xr0 = (float)vr[0], xr1 = (float)vr[1], xr2 = (float)vr[2], xr3 = (float)vr[3];

    int e0 = row_start[n], e1 = row_start[n + 1];
    float l0 = 0.f, l1 = 0.f;
    float4 a0 = {0.f, 0.f, 0.f, 0.f}, a1 = {0.f, 0.f, 0.f, 0.f};

    int j = e0;
    for (; j + 1 < e1; j += 2) {
        int s0 = ssrc[j], s1 = ssrc[j + 1];
        const f16x2* eah = (const f16x2*)(ea_h + (size_t)j * EDGE_DIM);
        f16x2 ep0[8], ep1[8];
#pragma unroll
        for (int kp = 0; kp < 8; kp++) ep0[kp] = eah[kp];
#pragma unroll
        for (int kp = 0; kp < 8; kp++) ep1[kp] = eah[8 + kp];
        bf16x4 vl0 = *(const bf16x4*)(xlr + (size_t)s0 * NCAT + c0);
        bf16x4 vl1 = *(const bf16x4*)(xlr + (size_t)s1 * NCAT + c0);

        float p0c0 = 0.f, p0c1 = 0.f, p0c2 = 0.f, p0c3 = 0.f;
        float p1c0 = 0.f, p1c1 = 0.f, p1c2 = 0.f, p1c3 = 0.f;
#pragma unroll
        for (int kp = 0; kp < 8; kp++) {
            p0c0 = __builtin_amdgcn_fdot2(wr[kp],      ep0[kp], p0c0, false);
            p1c0 = __builtin_amdgcn_fdot2(wr[kp],      ep1[kp], p1c0, false);
            p0c1 = __builtin_amdgcn_fdot2(wr[8 + kp],  ep0[kp], p0c1, false);
            p1c1 = __builtin_amdgcn_fdot2(wr[8 + kp],  ep1[kp], p1c1, false);
            p0c2 = __builtin_amdgcn_fdot2(wr[16 + kp], ep0[kp], p0c2, false);
            p1c2 = __builtin_amdgcn_fdot2(wr[16 + kp], ep1[kp], p1c2, false);
            p0c3 = __builtin_amdgcn_fdot2(wr[24 + kp], ep0[kp], p0c3, false);
            p1c3 = __builtin_amdgcn_fdot2(wr[24 + kp], ep1[kp], p1c3, false);
        }
        float x00 = (float)vl0[0], x01 = (float)vl0[1], x02 = (float)vl0[2], x03 = (float)vl0[3];
        float x10 = (float)vl1[0], x11 = (float)vl1[1], x12 = (float)vl1[2], x13 = (float)vl1[3];
        float m00 = x00 + xr0 + p0c0; m00 = fmaxf(m00, 0.2f * m00);
        float m01 = x01 + xr1 + p0c1; m01 = fmaxf(m01, 0.2f * m01);
        float m02 = x02 + xr2 + p0c2; m02 = fmaxf(m02, 0.2f * m02);
        float m03 = x03 + xr3 + p0c3; m03 = fmaxf(m03, 0.2f * m03);
        float m10 = x10 + xr0 + p1c0; m10 = fmaxf(m10, 0.2f * m10);
        float m11 = x11 + xr1 + p1c1; m11 = fmaxf(m11, 0.2f * m11);
        float m12 = x12 + xr2 + p1c2; m12 = fmaxf(m12, 0.2f * m12);
        float m13 = x13 + xr3 + p1c3; m13 = fmaxf(m13, 0.2f * m13);
        float part0 = m00 * att4.x + m01 * att4.y + m02 * att4.z + m03 * att4.w;
        float part1 = m10 * att4.x + m11 * att4.y + m12 * att4.z + m13 * att4.w;
#pragma unroll
        for (int off = 1; off < 32; off <<= 1) {
            part0 += __shfl_xor(part0, off, 64);
            part1 += __shfl_xor(part1, off, 64);
        }
        float p0 = __expf(part0);
        float p1 = __expf(part1);
        l0 += p0; l1 += p1;
        a0.x = fmaf(p0, x00, a0.x); a0.y = fmaf(p0, x01, a0.y);
        a0.z = fmaf(p0, x02, a0.z); a0.w = fmaf(p0, x03, a0.w);
        a1.x = fmaf(p1, x10, a1.x); a1.y = fmaf(p1, x11, a1.y);
        a1.z = fmaf(p1, x12, a1.z); a1.w = fmaf(p1, x13, a1.w);
    }
    if (j < e1) {
        int s0 = ssrc[j];
        const f16x2* eah = (const f16x2*)(ea_h + (size_t)j * EDGE_DIM);
        f16x2 ep0[8];
#pragma unroll
        for (int kp = 0; kp < 8; kp++) ep0[kp] = eah[kp];
        bf16x4 vl0 = *(const bf16x4*)(xlr + (size_t)s0 * NCAT + c0);
        float p0c0 = 0.f, p0c1 = 0.f, p0c2 = 0.f, p0c3 = 0.f;
#pragma unroll
        for (int kp = 0; kp < 8; kp++) {
            p0c0 = __builtin_amdgcn_fdot2(wr[kp],      ep0[kp], p0c0, false);
            p0c1 = __builtin_amdgcn_fdot2(wr[8 + kp],  ep0[kp], p0c1, false);
            p0c2 = __builtin_amdgcn_fdot2(wr[16 + kp], ep0[kp], p0c2, false);
            p0c3 = __builtin_amdgcn_fdot2(wr[24 + kp], ep0[kp], p0c3, false);
        }
        float x00 = (float)vl0[0], x01 = (float)vl0[1], x02 = (float)vl0[2], x03 = (float)vl0[3];
        float m00 = x00 + xr0 + p0c0; m00 = fmaxf(m00, 0.2f * m00);
        float m01 = x01 + xr1 + p0c1; m01 = fmaxf(m01, 0.2f * m01);
        float m02 = x02 + xr2 + p0c2; m02 = fmaxf(m02, 0.2f * m02);
        float m03 = x03 + xr3 + p0c3; m03 = fmaxf(m03, 0.2f * m03);
        float part0 = m00 * att4.x + m01 * att4.y + m02 * att4.z + m03 * att4.w;
#pragma unroll
        for (int off = 1; off < 32; off <<= 1) part0 += __shfl_xor(part0, off, 64);
        float p0 = __expf(part0);
        l0 += p0;
        a0.x = fmaf(p0, x00, a0.x); a0.y = fmaf(p0, x01, a0.y);
        a0.z = fmaf(p0, x02, a0.z); a0.w = fmaf(p0, x03, a0.w);
    }

    float inv = 1.f / (l0 + l1 + 1e-16f);

    __shared__ float sout[HC];
    __shared__ float red[4];
    sout[c0 + 0] = (a0.x + a1.x) * inv;
    sout[c0 + 1] = (a0.y + a1.y) * inv;
    sout[c0 + 2] = (a0.z + a1.z) * inv;
    sout[c0 + 3] = (a0.w + a1.w) * inv;
    __syncthreads();

    int c = t;
    float v = 0.25f * (sout[c] + sout[c + 128] + sout[c + 256] + sout[c + 384]) + bgat_l[c];
    float s1 = v, s2 = v * v;
#pragma unroll
    for (int off = 1; off < 64; off <<= 1) {
        s1 += __shfl_xor(s1, off, 64);
        s2 += __shfl_xor(s2, off, 64);
    }
    if (lane == 0) { red[wave * 2] = s1; red[wave * 2 + 1] = s2; }
    __syncthreads();
    s1 = red[0] + red[2];
    s2 = red[1] + red[3];
    float mu = s1 * (1.f / HID);
    float var = s2 * (1.f / HID) - mu * mu;
    float rstd = rsqrtf(var + 1e-5f);
    float y = fmaf(gamma_l[c] * (v - mu), rstd, beta_l[c]);
    y = elu_f(y);
    if (has_res) y += (float)xlr[(size_t)n * NCAT + 1024 + c];
    if (do_pool) atomicAdd(&hsum[(size_t)batch[n] * HID + c], y);
    else hbf_out[(size_t)n * HID + c] = (bf16)y;
}

// ---------------- MLP head ----------------
__global__ __launch_bounds__(128) void k_mlp(const float* __restrict__ hsum,
                                             const int* __restrict__ cnt,
                                             const float* __restrict__ W1, const float* __restrict__ b1,
                                             const float* __restrict__ W2, const float* __restrict__ b2,
                                             const float* __restrict__ W3, const float* __restrict__ b3,
                                             float* __restrict__ out) {
    int g = blockIdx.x, t = threadIdx.x;
    __shared__ float hg[HID], z1[HID], z2[64];
    float invc = 1.f / fmaxf((float)cnt[g], 1.f);
    hg[t] = hsum[(size_t)g * HID + t] * invc;
    __syncthreads();
    float s = b1[t];
#pragma unroll 8
    for (int k = 0; k < HID; k++) s = fmaf(hg[k], W1[k * HID + t], s);
    z1[t] = fmaxf(s, 0.f);
    __syncthreads();
    if (t < 64) {
        float s2 = b2[t];
#pragma unroll 8
        for (int k = 0; k < HID; k++) s2 = fmaf(z1[k], W2[k * 64 + t], s2);
        z2[t] = fmaxf(s2, 0.f);
    }
    __syncthreads();
    if (t < 64) {
        float s3 = z2[t] * W3[t];
#pragma unroll
        for (int off = 1; off < 64; off <<= 1) s3 += __shfl_xor(s3, off, 64);
        if (t == 0) out[g] = s3 + b3[0];
    }
}

// ---------------- host launcher ----------------
extern "C" void kernel_launch(void* const* d_in, const int* in_sizes, int n_in,
                              void* d_out, int out_size, void* d_ws, size_t ws_size,
                              hipStream_t stream) {
    const float* x         = (const float*)d_in[0];
    const int*   ei        = (const int*)  d_in[1];
    const float* edge_attr = (const float*)d_in[2];
    const int*   batch     = (const int*)  d_in[3];
    const float* Win       = (const float*)d_in[4];
    const float* b_in      = (const float*)d_in[5];
    const float* Wl        = (const float*)d_in[6];
    const float* bl        = (const float*)d_in[7];
    const float* Wr        = (const float*)d_in[8];
    const float* br        = (const float*)d_in[9];
    const float* We        = (const float*)d_in[10];
    const float* att       = (const float*)d_in[11];
    const float* b_gat     = (const float*)d_in[12];
    const float* gamma     = (const float*)d_in[13];
    const float* beta      = (const float*)d_in[14];
    const float* Wres      = (const float*)d_in[15];
    const float* bres      = (const float*)d_in[16];
    const float* W1        = (const float*)d_in[17];
    const float* b1        = (const float*)d_in[18];
    const float* W2        = (const float*)d_in[19];
    const float* b2        = (const float*)d_in[20];
    const float* W3        = (const float*)d_in[21];
    const float* b3        = (const float*)d_in[22];
    float* out = (float*)d_out;

    char* ws = (char*)d_ws;
    size_t off = 0;
    auto alloc = [&](size_t bytes) -> void* {
        void* p = ws + off;
        off = (off + bytes + 255) & ~(size_t)255;
        return p;
    };
    bf16*  h_bf    = (bf16*) alloc((size_t)N_NODES * HID * 2);
    bf16*  xlr     = (bf16*) alloc((size_t)N_NODES * NCAT * 2);
    bf16*  WT      = (bf16*) alloc((size_t)LAYERS * NCAT * HID * 2);
    float* bcat    = (float*)alloc((size_t)LAYERS * NCAT * 4);
    f16*   WeH     = (f16*)  alloc((size_t)LAYERS * HC * EDGE_DIM * 2);
    f16*   ea_h    = (f16*)  alloc((size_t)N_EDGES * EDGE_DIM * 2);
    // contiguous zero region: [hsum | cnt | deg]
    char*  zbase   = ws + off;
    float* hsum    = (float*)alloc((size_t)NUM_GRAPHS * HID * 4);
    int*   cnt     = (int*)  alloc((size_t)NUM_GRAPHS * 4);
    int*   deg     = (int*)  alloc((size_t)N_NODES * 4);
    size_t zlen    = (size_t)((ws + off) - zbase);
    int*   rowst   = (int*)  alloc((size_t)(N_NODES + 1) * 4);
    int*   cursor  = (int*)  alloc((size_t)N_NODES * 4);
    int*   ssrc    = (int*)  alloc((size_t)N_EDGES * 4);
    (void)ws_size; // requires ~33 MB

    hipMemsetAsync(zbase, 0, zlen, stream);

    k_prep_all<<<PREP_BLOCKS + DEG_BLOCKS + N_NODES, 128, 0, stream>>>(
        Wl, bl, Wr, br, Wres, bres, We, WT, bcat, WeH,
        ei, batch, deg, cnt, x, Win, b_in, h_bf);
    k_scan<<<1, 1024, 0, stream>>>(deg, rowst, cursor);
    k_scatter<<<(N_EDGES + 255) / 256, 256, 0, stream>>>(ei, edge_attr, cursor, ssrc, ea_h);

    const int MG = (N_NODES + 127) / 128;  // 79
    for (int i = 0; i < LAYERS; i++) {
        int ntiles = (i > 0) ? (NCAT / 128) : (1024 / 128);
        k_gemm_mfma<<<dim3(MG, ntiles), 256, 0, stream>>>(
            h_bf, WT + (size_t)i * NCAT * HID, bcat + (size_t)i * NCAT, xlr, N_NODES);
        k_edge_fused<<<N_NODES, 128, 0, stream>>>(
            xlr, ea_h, rowst, ssrc,
            WeH + (size_t)i * HC * EDGE_DIM, att + (size_t)i * HEADS * HID,
            b_gat + (size_t)i * HID, gamma + (size_t)i * HID, beta + (size_t)i * HID,
            (i > 0) ? 1 : 0,
            batch, hsum, (i == LAYERS - 1) ? 1 : 0, h_bf);
    }

    k_mlp<<<NUM_GRAPHS, 128, 0, stream>>>(hsum, cnt, W1, b1, W2, b2, W3, b3, out);
}

// Round 12
// 408.573 us; speedup vs baseline: 1.1511x; 1.0014x over previous
//
#include <hip/hip_runtime.h>

#define N_NODES 10000
#define N_EDGES 100000
#define IN_CH 64
#define EDGE_DIM 16
#define HID 128
#define HEADS 4
#define HC 512          // HEADS*HID
#define LAYERS 4
#define NUM_GRAPHS 256
#define NCAT 1152       // 512(xl) + 512(xr) + 128(res) packed cols
#define LDPK 72         // padded LDS stride for 64-elem K-chunk (bf16 elems)

#define PREP_BLOCKS 320 // 10 * LAYERS * 8
#define DEG_BLOCKS 782  // ceil(N_EDGES/128)

typedef __bf16 bf16;
typedef __bf16 bf16x8 __attribute__((ext_vector_type(8)));
typedef __bf16 bf16x4 __attribute__((ext_vector_type(4)));
typedef float floatx4 __attribute__((ext_vector_type(4)));
typedef _Float16 f16;
typedef _Float16 f16x2 __attribute__((ext_vector_type(2)));

__device__ __forceinline__ float elu_f(float x) { return x > 0.f ? x : (__expf(x) - 1.f); }

// ---------------- merged prep: weight repack + degree/count + h0 ----------------
__global__ __launch_bounds__(128) void k_prep_all(
    const float* __restrict__ Wl, const float* __restrict__ bl,
    const float* __restrict__ Wr, const float* __restrict__ br,
    const float* __restrict__ Wres, const float* __restrict__ bres,
    const float* __restrict__ We,
    bf16* __restrict__ WT, float* __restrict__ bcat, f16* __restrict__ WeH,
    const int* __restrict__ ei, const int* __restrict__ batch,
    int* __restrict__ deg, int* __restrict__ cnt,
    const float* __restrict__ x, const float* __restrict__ Win,
    const float* __restrict__ b_in, bf16* __restrict__ h_bf) {
    __shared__ float smem[16 * 129];
    int b = blockIdx.x;
    int t = threadIdx.x;

    if (b < PREP_BLOCKS) {
        int nt = b % 10, i = (b / 10) % LAYERS, z = b / 40;
        if (nt == 9) {
            if (z < 4) {
                int c = z * 128 + t;
                const float* src = We + (size_t)i * EDGE_DIM * HC + c;
                f16 buf[16];
#pragma unroll
                for (int k = 0; k < EDGE_DIM; k++) buf[k] = (f16)src[(size_t)k * HC];
                f16* dst = WeH + ((size_t)i * HC + c) * EDGE_DIM;
                *(uint4*)dst = *(uint4*)buf;
                *(uint4*)(dst + 8) = *(uint4*)(buf + 8);
            }
            return;
        }
        float (*tile)[129] = (float(*)[129])smem;
        int n0 = nt * 128;
        const float* base = nullptr; const float* bsrc = nullptr; int ld = 0;
        if (nt < 4)       { base = Wl + (size_t)i * HID * HC + n0;          bsrc = bl + i * HC + n0;              ld = HC; }
        else if (nt < 8)  { base = Wr + (size_t)i * HID * HC + (n0 - 512);  bsrc = br + i * HC + (n0 - 512);      ld = HC; }
        else if (i > 0)   { base = Wres + (size_t)(i - 1) * HID * HID;      bsrc = bres + (size_t)(i - 1) * HID;  ld = HID; }
        if (base) {
#pragma unroll
            for (int r = 0; r < 16; r++) tile[r][t] = base[(size_t)(z * 16 + r) * ld + t];
        } else {
#pragma unroll
            for (int r = 0; r < 16; r++) tile[r][t] = 0.f;
        }
        __syncthreads();
        int n = n0 + t;
        if (z == 0) bcat[(size_t)i * NCAT + n] = base ? bsrc[t] : 0.f;
        bf16* dst = WT + ((size_t)i * NCAT + n) * HID + z * 16;
#pragma unroll
        for (int kc = 0; kc < 2; kc++) {
            bf16x8 v;
#pragma unroll
            for (int u = 0; u < 8; u++) v[u] = (bf16)tile[kc * 8 + u][t];
            *(bf16x8*)(dst + kc * 8) = v;
        }
    } else if (b < PREP_BLOCKS + DEG_BLOCKS) {
        int e = (b - PREP_BLOCKS) * 128 + t;
        if (e < N_EDGES) atomicAdd(&deg[ei[N_EDGES + e]], 1);
        if (e < N_NODES) atomicAdd(&cnt[batch[e]], 1);
    } else {
        int n = b - (PREP_BLOCKS + DEG_BLOCKS);
        float* xs = smem;
        if (t < IN_CH) xs[t] = x[(size_t)n * IN_CH + t];
        __syncthreads();
        float s = b_in[t];
#pragma unroll 8
        for (int k = 0; k < IN_CH; k++) s = fmaf(xs[k], Win[k * HID + t], s);
        h_bf[(size_t)n * HID + t] = (bf16)elu_f(s);
    }
}

// ---------------- MFMA bf16 GEMM: C[M,NCAT] = A[M,128] @ WT^T + bias ------
__global__ __launch_bounds__(256) void k_gemm_mfma(
    const bf16* __restrict__ A, const bf16* __restrict__ WT,
    const float* __restrict__ bcat, bf16* __restrict__ C, int M) {
    __shared__ __align__(16) unsigned short As[128 * LDPK];
    __shared__ __align__(16) unsigned short Bs[128 * LDPK];
    int t = threadIdx.x;
    int r0 = blockIdx.x * 128, c0 = blockIdx.y * 128;

    int wave = t >> 6, lane = t & 63;
    int wm = wave & 1, wn = wave >> 1;
    int quad = lane >> 4, lm = lane & 15;
    floatx4 zero = {0.f, 0.f, 0.f, 0.f};
    floatx4 acc[4][4];
#pragma unroll
    for (int mi = 0; mi < 4; mi++)
#pragma unroll
        for (int ni = 0; ni < 4; ni++) acc[mi][ni] = zero;

    const unsigned short* Ab = &As[(wm * 64 + lm) * LDPK + quad * 8];
    const unsigned short* Bb = &Bs[(wn * 64 + lm) * LDPK + quad * 8];

    for (int kc = 0; kc < 2; kc++) {
#pragma unroll
        for (int i = 0; i < 4; i++) {
            int idx = t + i * 256;
            int row = idx >> 3;
            int ch = idx & 7;
            int r = r0 + row; if (r >= M) r = M - 1;
            *(uint4*)&As[row * LDPK + ch * 8] =
                *(const uint4*)(A + (size_t)r * HID + kc * 64 + ch * 8);
            *(uint4*)&Bs[row * LDPK + ch * 8] =
                *(const uint4*)(WT + (size_t)(c0 + row) * HID + kc * 64 + ch * 8);
        }
        __syncthreads();
#pragma unroll
        for (int ks = 0; ks < 2; ks++) {
            bf16x8 af[4], bfr[4];
#pragma unroll
            for (int mi = 0; mi < 4; mi++) af[mi] = *(const bf16x8*)(Ab + mi * 16 * LDPK + ks * 32);
#pragma unroll
            for (int ni = 0; ni < 4; ni++) bfr[ni] = *(const bf16x8*)(Bb + ni * 16 * LDPK + ks * 32);
#pragma unroll
            for (int mi = 0; mi < 4; mi++)
#pragma unroll
                for (int ni = 0; ni < 4; ni++)
                    acc[mi][ni] = __builtin_amdgcn_mfma_f32_16x16x32_bf16(bfr[ni], af[mi], acc[mi][ni], 0, 0, 0);
        }
        __syncthreads();
    }

#pragma unroll
    for (int mi = 0; mi < 4; mi++) {
        int row = r0 + wm * 64 + mi * 16 + lm;
        if (row < M) {
            bf16* crow = C + (size_t)row * NCAT;
#pragma unroll
            for (int ni = 0; ni < 4; ni++) {
                int cb = c0 + wn * 64 + ni * 16 + quad * 4;
                float4 b4 = *(const float4*)(bcat + cb);
                floatx4 v = acc[mi][ni];
                bf16x4 o = {(bf16)(v[0] + b4.x), (bf16)(v[1] + b4.y),
                            (bf16)(v[2] + b4.z), (bf16)(v[3] + b4.w)};
                *(bf16x4*)(crow + cb) = o;
            }
        }
    }
}

// shfl-based scan, 4 elems/thread
__global__ __launch_bounds__(1024) void k_scan(const int* __restrict__ deg,
                                               int* __restrict__ row_start,
                                               int* __restrict__ cursor) {
    __shared__ int wsum[16];
    __shared__ int carry_s;
    int t = threadIdx.x;
    int wave = t >> 6, lane = t & 63;
    if (t == 0) { carry_s = 0; row_start[0] = 0; }
    __syncthreads();
    for (int base = 0; base < N_NODES; base += 4096) {
        int i0 = base + t * 4;
        int v[4];
#pragma unroll
        for (int u = 0; u < 4; u++) v[u] = (i0 + u < N_NODES) ? deg[i0 + u] : 0;
        int tsum = v[0] + v[1] + v[2] + v[3];
        int incl = tsum;
#pragma unroll
        for (int off = 1; off < 64; off <<= 1) {
            int u = __shfl_up(incl, off, 64);
            if (lane >= off) incl += u;
        }
        if (lane == 63) wsum[wave] = incl;
        __syncthreads();
        if (wave == 0) {
            int ws = (lane < 16) ? wsum[lane] : 0;
#pragma unroll
            for (int off = 1; off < 16; off <<= 1) {
                int u = __shfl_up(ws, off, 64);
                if (lane >= off) ws += u;
            }
            if (lane < 16) wsum[lane] = ws;
        }
        __syncthreads();
        int carry = carry_s;
        int chunk_total = wsum[15];
        int p = carry + ((wave == 0) ? 0 : wsum[wave - 1]) + incl - tsum;
#pragma unroll
        for (int u = 0; u < 4; u++) {
            int i = i0 + u;
            if (i < N_NODES) { cursor[i] = p; p += v[u]; row_start[i + 1] = p; }
        }
        __syncthreads();
        if (t == 0) carry_s = carry + chunk_total;
    }
}

// scatter edges into CSR order; permute + f16-convert edge_attr
__global__ void k_scatter(const int* __restrict__ ei, const float* __restrict__ edge_attr,
                          int* __restrict__ cursor,
                          int* __restrict__ ssrc, f16* __restrict__ ea_h) {
    int e = blockIdx.x * blockDim.x + threadIdx.x;
    if (e < N_EDGES) {
        int d = ei[N_EDGES + e];
        int pos = atomicAdd(&cursor[d], 1);
        ssrc[pos] = ei[e];
        const float* s = edge_attr + (size_t)e * EDGE_DIM;
        f16 buf[16];
#pragma unroll
        for (int q = 0; q < 16; q++) buf[q] = (f16)s[q];
        f16* dst = ea_h + (size_t)pos * EDGE_DIM;
        *(uint4*)dst = *(uint4*)buf;
        *(uint4*)(dst + 8) = *(uint4*)(buf + 8);
    }
}

// ---------------- fused edge phase: ONE WAVE per node, 8 ch/lane ------------
// head = lane>>4 -> logit reduction over 16 lanes = 4 shfls (was 5 over 32).
// Each edge's ssrc/ea/We issued by one wave (was duplicated across 2).
// No inter-wave barriers in the hot loop. Unroll-2 dual chains.
__global__ __launch_bounds__(64) void k_edge_fused(
    const bf16* __restrict__ xlr, const f16* __restrict__ ea_h,
    const int* __restrict__ row_start, const int* __restrict__ ssrc,
    const f16* __restrict__ WeH_l, const float* __restrict__ att_l,
    const float* __restrict__ bgat_l, const float* __restrict__ gamma_l,
    const float* __restrict__ beta_l,
    int has_res,
    const int* __restrict__ batch, float* __restrict__ hsum, int do_pool,
    bf16* __restrict__ hbf_out) {
    int n = blockIdx.x;
    int lane = threadIdx.x;          // 0..63
    int c0 = lane * 8;               // 8 contiguous channels of the 512
    int head = lane >> 4;            // 16 lanes per head

    const f16x2* wr = (const f16x2*)(WeH_l + (size_t)c0 * EDGE_DIM); // 64 f16x2, 256B contiguous
    int ca = (lane & 15) * 8;        // channel-within-head
    float4 attA = *(const float4*)(att_l + head * HID + ca);
    float4 attB = *(const float4*)(att_l + head * HID + ca + 4);
    bf16x8 vr8 = *(const bf16x8*)(xlr + (size_t)n * NCAT + 512 + c0);
    float xr[8];
#pragma unroll
    for (int c = 0; c < 8; c++) xr[c] = (float)vr8[c];

    int e0 = row_start[n], e1 = row_start[n + 1];
    float l0 = 0.f, l1 = 0.f;
    float a0[8], a1[8];
#pragma unroll
    for (int c = 0; c < 8; c++) { a0[c] = 0.f; a1[c] = 0.f; }

    int j = e0;
    for (; j + 1 < e1; j += 2) {
        int s0 = ssrc[j], s1 = ssrc[j + 1];
        const f16x2* eah = (const f16x2*)(ea_h + (size_t)j * EDGE_DIM);
        f16x2 ep0[8], ep1[8];
#pragma unroll
        for (int kp = 0; kp < 8; kp++) ep0[kp] = eah[kp];
#pragma unroll
        for (int kp = 0; kp < 8; kp++) ep1[kp] = eah[8 + kp];
        bf16x8 vl0 = *(const bf16x8*)(xlr + (size_t)s0 * NCAT + c0);
        bf16x8 vl1 = *(const bf16x8*)(xlr + (size_t)s1 * NCAT + c0);

        float part0 = 0.f, part1 = 0.f;
        float x0[8], x1[8];
#pragma unroll
        for (int c = 0; c < 8; c++) {
            float ec0 = 0.f, ec1 = 0.f;
#pragma unroll
            for (int kp = 0; kp < 8; kp++) {
                ec0 = __builtin_amdgcn_fdot2(wr[c * 8 + kp], ep0[kp], ec0, false);
                ec1 = __builtin_amdgcn_fdot2(wr[c * 8 + kp], ep1[kp], ec1, false);
            }
            x0[c] = (float)vl0[c];
            x1[c] = (float)vl1[c];
            float att_c = (c < 4) ? ((const float*)&attA)[c] : ((const float*)&attB)[c - 4];
            float m0 = x0[c] + xr[c] + ec0; m0 = fmaxf(m0, 0.2f * m0);
            float m1 = x1[c] + xr[c] + ec1; m1 = fmaxf(m1, 0.2f * m1);
            part0 = fmaf(m0, att_c, part0);
            part1 = fmaf(m1, att_c, part1);
        }
#pragma unroll
        for (int off = 1; off < 16; off <<= 1) {
            part0 += __shfl_xor(part0, off, 64);
            part1 += __shfl_xor(part1, off, 64);
        }
        float p0 = __expf(part0);
        float p1 = __expf(part1);
        l0 += p0; l1 += p1;
#pragma unroll
        for (int c = 0; c < 8; c++) {
            a0[c] = fmaf(p0, x0[c], a0[c]);
            a1[c] = fmaf(p1, x1[c], a1[c]);
        }
    }
    if (j < e1) {
        int s0 = ssrc[j];
        const f16x2* eah = (const f16x2*)(ea_h + (size_t)j * EDGE_DIM);
        f16x2 ep0[8];
#pragma unroll
        for (int kp = 0; kp < 8; kp++) ep0[kp] = eah[kp];
        bf16x8 vl0 = *(const bf16x8*)(xlr + (size_t)s0 * NCAT + c0);
        float part0 = 0.f;
        float x0[8];
#pragma unroll
        for (int c = 0; c < 8; c++) {
            float ec0 = 0.f;
#pragma unroll
            for (int kp = 0; kp < 8; kp++)
                ec0 = __builtin_amdgcn_fdot2(wr[c * 8 + kp], ep0[kp], ec0, false);
            x0[c] = (float)vl0[c];
            float att_c = (c < 4) ? ((const float*)&attA)[c] : ((const float*)&attB)[c - 4];
            float m0 = x0[c] + xr[c] + ec0; m0 = fmaxf(m0, 0.2f * m0);
            part0 = fmaf(m0, att_c, part0);
        }
#pragma unroll
        for (int off = 1; off < 16; off <<= 1) part0 += __shfl_xor(part0, off, 64);
        float p0 = __expf(part0);
        l0 += p0;
#pragma unroll
        for (int c = 0; c < 8; c++) a0[c] = fmaf(p0, x0[c], a0[c]);
    }

    float inv = 1.f / (l0 + l1 + 1e-16f);

    __shared__ float sout[HC];
    {
        float4 o0 = {(a0[0] + a1[0]) * inv, (a0[1] + a1[1]) * inv,
                     (a0[2] + a1[2]) * inv, (a0[3] + a1[3]) * inv};
        float4 o1 = {(a0[4] + a1[4]) * inv, (a0[5] + a1[5]) * inv,
                     (a0[6] + a1[6]) * inv, (a0[7] + a1[7]) * inv};
        *(float4*)&sout[c0] = o0;
        *(float4*)&sout[c0 + 4] = o1;
    }
    __syncthreads();   // single-wave block: cheap

    // two output channels per lane: c = lane, lane+64
    int cA = lane, cB = lane + 64;
    float v0 = 0.25f * (sout[cA] + sout[cA + 128] + sout[cA + 256] + sout[cA + 384]) + bgat_l[cA];
    float v1 = 0.25f * (sout[cB] + sout[cB + 128] + sout[cB + 256] + sout[cB + 384]) + bgat_l[cB];
    float s1 = v0 + v1, s2 = v0 * v0 + v1 * v1;
#pragma unroll
    for (int off = 1; off < 64; off <<= 1) {
        s1 += __shfl_xor(s1, off, 64);
        s2 += __shfl_xor(s2, off, 64);
    }
    float mu = s1 * (1.f / HID);
    float var = s2 * (1.f / HID) - mu * mu;
    float rstd = rsqrtf(var + 1e-5f);
    float y0 = fmaf(gamma_l[cA] * (v0 - mu), rstd, beta_l[cA]);
    float y1 = fmaf(gamma_l[cB] * (v1 - mu), rstd, beta_l[cB]);
    y0 = elu_f(y0);
    y1 = elu_f(y1);
    if (has_res) {
        y0 += (float)xlr[(size_t)n * NCAT + 1024 + cA];
        y1 += (float)xlr[(size_t)n * NCAT + 1024 + cB];
    }
    if (do_pool) {
        int g = batch[n];
        atomicAdd(&hsum[(size_t)g * HID + cA], y0);
        atomicAdd(&hsum[(size_t)g * HID + cB], y1);
    } else {
        hbf_out[(size_t)n * HID + cA] = (bf16)y0;
        hbf_out[(size_t)n * HID + cB] = (bf16)y1;
    }
}

// ---------------- MLP head ----------------
__global__ __launch_bounds__(128) void k_mlp(const float* __restrict__ hsum,
                                             const int* __restrict__ cnt,
                                             const float* __restrict__ W1, const float* __restrict__ b1,
                                             const float* __restrict__ W2, const float* __restrict__ b2,
                                             const float* __restrict__ W3, const float* __restrict__ b3,
                                             float* __restrict__ out) {
    int g = blockIdx.x, t = threadIdx.x;
    __shared__ float hg[HID], z1[HID], z2[64];
    float invc = 1.f / fmaxf((float)cnt[g], 1.f);
    hg[t] = hsum[(size_t)g * HID + t] * invc;
    __syncthreads();
    float s = b1[t];
#pragma unroll 8
    for (int k = 0; k < HID; k++) s = fmaf(hg[k], W1[k * HID + t], s);
    z1[t] = fmaxf(s, 0.f);
    __syncthreads();
    if (t < 64) {
        float s2 = b2[t];
#pragma unroll 8
        for (int k = 0; k < HID; k++) s2 = fmaf(z1[k], W2[k * 64 + t], s2);
        z2[t] = fmaxf(s2, 0.f);
    }
    __syncthreads();
    if (t < 64) {
        float s3 = z2[t] * W3[t];
#pragma unroll
        for (int off = 1; off < 64; off <<= 1) s3 += __shfl_xor(s3, off, 64);
        if (t == 0) out[g] = s3 + b3[0];
    }
}

// ---------------- host launcher ----------------
extern "C" void kernel_launch(void* const* d_in, const int* in_sizes, int n_in,
                              void* d_out, int out_size, void* d_ws, size_t ws_size,
                              hipStream_t stream) {
    const float* x         = (const float*)d_in[0];
    const int*   ei        = (const int*)  d_in[1];
    const float* edge_attr = (const float*)d_in[2];
    const int*   batch     = (const int*)  d_in[3];
    const float* Win       = (const float*)d_in[4];
    const float* b_in      = (const float*)d_in[5];
    const float* Wl        = (const float*)d_in[6];
    const float* bl        = (const float*)d_in[7];
    const float* Wr        = (const float*)d_in[8];
    const float* br        = (const float*)d_in[9];
    const float* We        = (const float*)d_in[10];
    const float* att       = (const float*)d_in[11];
    const float* b_gat     = (const float*)d_in[12];
    const float* gamma     = (const float*)d_in[13];
    const float* beta      = (const float*)d_in[14];
    const float* Wres      = (const float*)d_in[15];
    const float* bres      = (const float*)d_in[16];
    const float* W1        = (const float*)d_in[17];
    const float* b1        = (const float*)d_in[18];
    const float* W2        = (const float*)d_in[19];
    const float* b2        = (const float*)d_in[20];
    const float* W3        = (const float*)d_in[21];
    const float* b3        = (const float*)d_in[22];
    float* out = (float*)d_out;

    char* ws = (char*)d_ws;
    size_t off = 0;
    auto alloc = [&](size_t bytes) -> void* {
        void* p = ws + off;
        off = (off + bytes + 255) & ~(size_t)255;
        return p;
    };
    bf16*  h_bf    = (bf16*) alloc((size_t)N_NODES * HID * 2);
    bf16*  xlr     = (bf16*) alloc((size_t)N_NODES * NCAT * 2);
    bf16*  WT      = (bf16*) alloc((size_t)LAYERS * NCAT * HID * 2);
    float* bcat    = (float*)alloc((size_t)LAYERS * NCAT * 4);
    f16*   WeH     = (f16*)  alloc((size_t)LAYERS * HC * EDGE_DIM * 2);
    f16*   ea_h    = (f16*)  alloc((size_t)N_EDGES * EDGE_DIM * 2);
    // contiguous zero region: [hsum | cnt | deg]
    char*  zbase   = ws + off;
    float* hsum    = (float*)alloc((size_t)NUM_GRAPHS * HID * 4);
    int*   cnt     = (int*)  alloc((size_t)NUM_GRAPHS * 4);
    int*   deg     = (int*)  alloc((size_t)N_NODES * 4);
    size_t zlen    = (size_t)((ws + off) - zbase);
    int*   rowst   = (int*)  alloc((size_t)(N_NODES + 1) * 4);
    int*   cursor  = (int*)  alloc((size_t)N_NODES * 4);
    int*   ssrc    = (int*)  alloc((size_t)N_EDGES * 4);
    (void)ws_size; // requires ~33 MB

    hipMemsetAsync(zbase, 0, zlen, stream);

    k_prep_all<<<PREP_BLOCKS + DEG_BLOCKS + N_NODES, 128, 0, stream>>>(
        Wl, bl, Wr, br, Wres, bres, We, WT, bcat, WeH,
        ei, batch, deg, cnt, x, Win, b_in, h_bf);
    k_scan<<<1, 1024, 0, stream>>>(deg, rowst, cursor);
    k_scatter<<<(N_EDGES + 255) / 256, 256, 0, stream>>>(ei, edge_attr, cursor, ssrc, ea_h);

    const int MG = (N_NODES + 127) / 128;  // 79
    for (int i = 0; i < LAYERS; i++) {
        int ntiles = (i > 0) ? (NCAT / 128) : (1024 / 128);
        k_gemm_mfma<<<dim3(MG, ntiles), 256, 0, stream>>>(
            h_bf, WT + (size_t)i * NCAT * HID, bcat + (size_t)i * NCAT, xlr, N_NODES);
        k_edge_fused<<<N_NODES, 64, 0, stream>>>(
            xlr, ea_h, rowst, ssrc,
            WeH + (size_t)i * HC * EDGE_DIM, att + (size_t)i * HEADS * HID,
            b_gat + (size_t)i * HID, gamma + (size_t)i * HID, beta + (size_t)i * HID,
            (i > 0) ? 1 : 0,
            batch, hsum, (i == LAYERS - 1) ? 1 : 0, h_bf);
    }

    k_mlp<<<NUM_GRAPHS, 128, 0, stream>>>(hsum, cnt, W1, b1, W2, b2, W3, b3, out);
}